// Round 6
// baseline (3858.332 us; speedup 1.0000x reference)
//
#include <hip/hip_runtime.h>

typedef short short8 __attribute__((ext_vector_type(8)));
typedef float f32x4 __attribute__((ext_vector_type(4)));
typedef unsigned int u32x4 __attribute__((ext_vector_type(4)));
typedef unsigned int u32x2 __attribute__((ext_vector_type(2)));

#define T_STEPS 512
#define BATCH   128
#define EMBD    512
#define HID     1024
#define NWG     256
#define NTHR    1024
#define NGROUP  8
#define WPG     32     // workgroups per group

// ---- workspace layout (bytes) ----
#define SLOT_STRIDE 16
#define SLOT_BYTES  (NWG * SLOT_STRIDE * 4)       // 16384
#define GR_OFF    SLOT_BYTES                      // 8 group flags, stride 128 B
#define GR_BYTES  1024
#define H_OFF     (SLOT_BYTES + GR_BYTES)         // 17408
#define H_BYTES   (NGROUP * 2 * 32768)            // 524288 (32 KB per group-buf)
#define WH_OFF    (H_OFF + H_BYTES)               // 541696
#define WH_BYTES  (32u*32u*8u*64u*8u*2u)          // 8388608
#define WI_OFF    (WH_OFF + WH_BYTES)
#define WI_BYTES  (32u*16u*8u*64u*8u*2u)          // 4194304
#define BS_OFF    (WI_OFF + WI_BYTES)
#define BS_BYTES  (4096 * 4)
#define PT_OFF    (BS_OFF + BS_BYTES)
#define PT_BYTES  (BATCH * 32 * 2 * 4)            // 32768
#define EMB_OFF   (PT_OFF + PT_BYTES)
#define EMB_BYTES ((size_t)T_STEPS*16*8*64*8*2)   // 67108864
#define WS_NEEDED (EMB_OFF + EMB_BYTES)

__device__ __forceinline__ unsigned short f2b(float f) {
    unsigned u = __builtin_bit_cast(unsigned, f);
    u += 0x7FFFu + ((u >> 16) & 1u);
    return (unsigned short)(u >> 16);
}

__device__ __forceinline__ uint4 pack8(float4 a, float4 b) {
    uint4 r;
    r.x = (unsigned)f2b(a.x) | ((unsigned)f2b(a.y) << 16);
    r.y = (unsigned)f2b(a.z) | ((unsigned)f2b(a.w) << 16);
    r.z = (unsigned)f2b(b.x) | ((unsigned)f2b(b.y) << 16);
    r.w = (unsigned)f2b(b.z) | ((unsigned)f2b(b.w) << 16);
    return r;
}

__device__ __forceinline__ float fsig(float x) {
    float e = __expf(-fabsf(x));
    float r = 1.f / (1.f + e);
    return x >= 0.f ? r : 1.f - r;
}
__device__ __forceinline__ float ftanh_(float x) {
    float e = __expf(-2.f * fabsf(x));
    float r = (1.f - e) / (1.f + e);
    return x >= 0.f ? r : -r;
}

// LLC-coherent (L1/L2-bypass) wide ops
__device__ __forceinline__ void llc_load16(const void* p, u32x4& v) {
    asm volatile("global_load_dwordx4 %0, %1, off sc0 sc1" : "=v"(v) : "v"(p));
}
__device__ __forceinline__ void llc_store8(void* p, u32x2 v) {
    asm volatile("global_store_dwordx2 %0, %1, off sc0 sc1" :: "v"(p), "v"(v) : "memory");
}
__device__ __forceinline__ void waitvm0() {
    asm volatile("s_waitcnt vmcnt(0)" ::: "memory");
}

// W_hh [4096,1024] -> wh_arr[w][ks(32)][nq(8)][lane][8]
__global__ void prep_wh(const float* __restrict__ w_hh, unsigned short* __restrict__ wh_arr) {
    int gid = blockIdx.x * blockDim.x + threadIdx.x;   // < 524288
    int l  = gid & 63;
    int nq = (gid >> 6) & 7;
    int ks = (gid >> 9) & 31;
    int w  = gid >> 14;
    int lr = nq * 16 + (l & 15);                       // 0..127
    int grow = (lr >> 5) * HID + w * 32 + (lr & 31);   // gate*1024 + col
    int k = ks * 32 + (l >> 4) * 8;
    const float4* src = reinterpret_cast<const float4*>(w_hh + (size_t)grow * HID + k);
    *reinterpret_cast<uint4*>(wh_arr + (size_t)gid * 8) = pack8(src[0], src[1]);
}

// W_ih [4096,512] -> wi_arr[w][eks(16)][nq(8)][lane][8]
__global__ void prep_wi(const float* __restrict__ w_ih, unsigned short* __restrict__ wi_arr) {
    int gid = blockIdx.x * blockDim.x + threadIdx.x;   // < 262144
    int l  = gid & 63;
    int nq = (gid >> 6) & 7;
    int eks = (gid >> 9) & 15;
    int w  = gid >> 13;
    int lr = nq * 16 + (l & 15);
    int grow = (lr >> 5) * HID + w * 32 + (lr & 31);
    int k = eks * 32 + (l >> 4) * 8;
    const float4* src = reinterpret_cast<const float4*>(w_ih + (size_t)grow * EMBD + k);
    *reinterpret_cast<uint4*>(wi_arr + (size_t)gid * 8) = pack8(src[0], src[1]);
}

__global__ void prep_bsum(const float* __restrict__ b_ih, const float* __restrict__ b_hh,
                          float* __restrict__ bs) {
    int gid = blockIdx.x * blockDim.x + threadIdx.x;   // < 4096
    int w = gid >> 7, lr = gid & 127;
    int grow = (lr >> 5) * HID + w * 32 + (lr & 31);
    bs[gid] = b_ih[grow] + b_hh[grow];
}

// embedded bf16 fragment chunks: emb_arr[t][eks(16)][mt(8)][lane][8]  (mt == group)
__global__ void prep_emb(const int* __restrict__ x, const float* __restrict__ emb,
                         unsigned short* __restrict__ emb_arr) {
    int gid = blockIdx.x * blockDim.x + threadIdx.x;   // < 512*16*8*64
    int l  = gid & 63;
    int mt = (gid >> 6) & 7;
    int ks = (gid >> 9) & 15;
    int t  = gid >> 13;
    int b  = mt * 16 + (l & 15);
    int k  = ks * 32 + (l >> 4) * 8;
    int tok = x[t * BATCH + b];
    const float4* src = reinterpret_cast<const float4*>(emb + (size_t)tok * EMBD + k);
    *reinterpret_cast<uint4*>(emb_arr + (size_t)gid * 8) = pack8(src[0], src[1]);
}

__global__ __launch_bounds__(NTHR) void lstm_main(
    const unsigned short* __restrict__ wh_arr,
    const unsigned short* __restrict__ wi_arr,
    const float* __restrict__ bs_arr,
    const unsigned short* __restrict__ emb_arr,
    unsigned short* __restrict__ h_arr,
    const float* __restrict__ fc_w,
    float* __restrict__ partials,
    unsigned* __restrict__ slots)
{
    __shared__ __align__(16) unsigned short wis[16 * 8 * 64 * 8];  // 131072 B
    __shared__ __align__(16) char ovl[32768];                      // stage / gbuf / fc overlay
    float* gbf    = reinterpret_cast<float*>(ovl);                 // [2][16][132]
    u32x4* stage4 = reinterpret_cast<u32x4*>(ovl);                 // [2048]
    unsigned short* stage = reinterpret_cast<unsigned short*>(ovl);

    unsigned* gr = slots + (GR_OFF >> 2);

    const int tid  = threadIdx.x;
    const int wgid = blockIdx.x;
    const int g = wgid >> 5;      // group 0..7 (batch rows 16g..16g+15)
    const int w = wgid & 31;      // gate-slice 0..31 (h cols 32w..32w+31)

    {   // one-time LDS fill of W_ih slice
        const uint4* s2 = reinterpret_cast<const uint4*>(wi_arr + (size_t)w * 65536);
        uint4* d2 = reinterpret_cast<uint4*>(wis);
        for (int i = tid; i < 8192; i += NTHR) d2[i] = s2[i];
    }

    const int lane = tid & 63;
    const int wave = tid >> 6;    // 0..15
    const int nq   = wave >> 1;   // n-tile 0..7 (16 gate rows each)
    const int kq   = wave & 1;    // k-half

    // W_hh B-fragments: persistent registers
    short8 bh[16];
    #pragma unroll
    for (int s = 0; s < 16; ++s) {
        int ks = kq * 16 + s;
        bh[s] = *reinterpret_cast<const short8*>(wh_arr + (size_t)(((w * 32 + ks) * 8 + nq) * 64 + lane) * 8);
    }

    // bias folded into acc-init (kq==0 only); D col n = lrD
    const int lrD   = nq * 16 + (lane & 15);
    const int rbase = (lane >> 4) * 4;
    const float bini = (kq == 0) ? bs_arr[w * 128 + lrD] : 0.f;

    // pointwise ownership (tid<128): batch row b, col quad qd (4 cols)
    const int pb = tid & 15;
    const int qd = tid >> 4;       // 0..7 when tid<128
    float cs[4] = {0.f, 0.f, 0.f, 0.f};
    float hr[4] = {0.f, 0.f, 0.f, 0.f};

    __syncthreads();

    for (int t = 0; t < T_STEPS; ++t) {
        f32x4 acc = {bini, bini, bini, bini};

        // ---- emb part: independent of h, overlaps barrier skew ----
        const unsigned short* ebuf = emb_arr + (size_t)t * 65536;
        #pragma unroll
        for (int s = 0; s < 8; ++s) {
            int eks = kq * 8 + s;
            short8 a  = *reinterpret_cast<const short8*>(ebuf + ((eks * 8 + g) * 64 + lane) * 8);
            short8 bw = *reinterpret_cast<const short8*>(wis + ((eks * 8 + nq) * 64 + lane) * 8);
            acc = __builtin_amdgcn_mfma_f32_16x16x32_bf16(a, bw, acc, 0, 0, 0);
        }

        if (t > 0) {
            // ---- aggregated group barrier ----
            if (w == 0) {
                if (tid < WPG) {
                    while (__hip_atomic_load(&slots[(g * WPG + tid) * SLOT_STRIDE],
                                             __ATOMIC_RELAXED, __HIP_MEMORY_SCOPE_AGENT) < (unsigned)t) {}
                }
                asm volatile("" ::: "memory");
                if (tid == 0)
                    __hip_atomic_store(&gr[g * 32], (unsigned)t,
                                       __ATOMIC_RELAXED, __HIP_MEMORY_SCOPE_AGENT);
            } else {
                if (tid == 0) {
                    while (__hip_atomic_load(&gr[g * 32],
                                             __ATOMIC_RELAXED, __HIP_MEMORY_SCOPE_AGENT) < (unsigned)t) {}
                }
            }
            __syncthreads();                       // S1: poll done

            // ---- stage group h (32 KB) into LDS: 2 x 16B per thread ----
            const char* hb = reinterpret_cast<const char*>(h_arr) + (size_t)(g * 2 + (t & 1)) * 32768;
            u32x4 v0, v1;
            llc_load16(hb + tid * 16, v0);
            llc_load16(hb + (tid + 1024) * 16, v1);
            waitvm0();
            __builtin_amdgcn_sched_barrier(0);
            stage4[tid] = v0;
            stage4[tid + 1024] = v1;
            __syncthreads();                       // S2: stage ready

            #pragma unroll
            for (int s = 0; s < 16; ++s) {
                int ks = kq * 16 + s;
                short8 a = *reinterpret_cast<const short8*>(stage + (ks * 64 + lane) * 8);
                acc = __builtin_amdgcn_mfma_f32_16x16x32_bf16(a, bh[s], acc, 0, 0, 0);
            }
        }
        __syncthreads();                           // S3: stage reads done before gbuf overwrite

        #pragma unroll
        for (int jj = 0; jj < 4; ++jj)
            gbf[kq * 2112 + (rbase + jj) * 132 + lrD] = acc[jj];
        __syncthreads();                           // S4: gates ready

        if (tid < 128) {   // pointwise: 4 cols (qd*4..+4) of batch row pb
            const float* g0 = gbf + pb * 132;
            const float* g1 = gbf + 2112 + pb * 132;
            const int cb = qd * 4;
            float4 xi = *reinterpret_cast<const float4*>(g0 + cb);
            float4 xf = *reinterpret_cast<const float4*>(g0 + 32 + cb);
            float4 xg = *reinterpret_cast<const float4*>(g0 + 64 + cb);
            float4 xo = *reinterpret_cast<const float4*>(g0 + 96 + cb);
            float4 yi = *reinterpret_cast<const float4*>(g1 + cb);
            float4 yf = *reinterpret_cast<const float4*>(g1 + 32 + cb);
            float4 yg = *reinterpret_cast<const float4*>(g1 + 64 + cb);
            float4 yo = *reinterpret_cast<const float4*>(g1 + 96 + cb);
            float ti[4] = {xi.x + yi.x, xi.y + yi.y, xi.z + yi.z, xi.w + yi.w};
            float tf[4] = {xf.x + yf.x, xf.y + yf.y, xf.z + yf.z, xf.w + yf.w};
            float tg[4] = {xg.x + yg.x, xg.y + yg.y, xg.z + yg.z, xg.w + yg.w};
            float to[4] = {xo.x + yo.x, xo.y + yo.y, xo.z + yo.z, xo.w + yo.w};
            #pragma unroll
            for (int e = 0; e < 4; ++e) {
                float ig = fsig(ti[e]), fg = fsig(tf[e]), gg = ftanh_(tg[e]), og = fsig(to[e]);
                cs[e] = fg * cs[e] + ig * gg;
                hr[e] = og * ftanh_(cs[e]);
            }
            u32x2 pk;
            pk.x = (unsigned)f2b(hr[0]) | ((unsigned)f2b(hr[1]) << 16);
            pk.y = (unsigned)f2b(hr[2]) | ((unsigned)f2b(hr[3]) << 16);
            char* hd = reinterpret_cast<char*>(h_arr) + (size_t)(g * 2 + ((t + 1) & 1)) * 32768;
            llc_store8(hd + (w * 64 + (qd >> 1) * 16 + pb) * 16 + (qd & 1) * 8, pk);
            waitvm0();   // h durable at LLC before this wave passes the barrier
        }
        __syncthreads();                           // S5: all h stores drained
        if (tid == 0) {
            __hip_atomic_store(&slots[(g * WPG + w) * SLOT_STRIDE], (unsigned)(t + 1),
                               __ATOMIC_RELAXED, __HIP_MEMORY_SCOPE_AGENT);
        }
    }

    // ---- FC head: deterministic two-stage reduce via LDS ----
    __syncthreads();
    float* red = reinterpret_cast<float*>(ovl);
    if (tid < 128) {
        float v0 = 0.f, v1 = 0.f;
        #pragma unroll
        for (int e = 0; e < 4; ++e) {
            int col = w * 32 + qd * 4 + e;
            v0 += hr[e] * fc_w[col];
            v1 += hr[e] * fc_w[HID + col];
        }
        red[tid * 2]     = v0;
        red[tid * 2 + 1] = v1;
    }
    __syncthreads();
    if (tid < 32) {
        int b = tid >> 1, o = tid & 1;
        float s = 0.f;
        for (int q = 0; q < 8; ++q) s += red[((q << 4) | b) * 2 + o];
        partials[((g * 16 + b) * 32 + w) * 2 + o] = s;
    }
}

__global__ void finalize(const float* __restrict__ partials, const float* __restrict__ fc_b,
                         float* __restrict__ out) {
    int tid = threadIdx.x;             // 256
    int b = tid >> 1, o = tid & 1;
    float s = fc_b[o];
    for (int w = 0; w < 32; ++w) s += partials[(b * 32 + w) * 2 + o];
    out[b * 2 + o] = s;
}

extern "C" void kernel_launch(void* const* d_in, const int* in_sizes, int n_in,
                              void* d_out, int out_size, void* d_ws, size_t ws_size,
                              hipStream_t stream) {
    const int*   x    = (const int*)d_in[0];
    const float* emb  = (const float*)d_in[1];
    const float* w_ih = (const float*)d_in[2];
    const float* w_hh = (const float*)d_in[3];
    const float* b_ih = (const float*)d_in[4];
    const float* b_hh = (const float*)d_in[5];
    const float* fc_w = (const float*)d_in[6];
    const float* fc_b = (const float*)d_in[7];
    float* out = (float*)d_out;
    char* ws = (char*)d_ws;

    if (ws_size < WS_NEEDED) {
        (void)hipMemsetAsync(d_out, 0xFF, (size_t)out_size * sizeof(float), stream);
        return;
    }

    unsigned*       slots   = (unsigned*)(ws);
    unsigned short* h_arr   = (unsigned short*)(ws + H_OFF);
    unsigned short* wh_arr  = (unsigned short*)(ws + WH_OFF);
    unsigned short* wi_arr  = (unsigned short*)(ws + WI_OFF);
    float*          bs_arr  = (float*)(ws + BS_OFF);
    float*          pt_arr  = (float*)(ws + PT_OFF);
    unsigned short* emb_arr = (unsigned short*)(ws + EMB_OFF);

    // zero arrival slots + group flags
    (void)hipMemsetAsync(ws, 0, SLOT_BYTES + GR_BYTES, stream);

    prep_wh  <<<2048, 256, 0, stream>>>(w_hh, wh_arr);
    prep_wi  <<<1024, 256, 0, stream>>>(w_ih, wi_arr);
    prep_bsum<<<16,   256, 0, stream>>>(b_ih, b_hh, bs_arr);
    prep_emb <<<16384,256, 0, stream>>>(x, emb, emb_arr);
    lstm_main<<<NWG, NTHR, 0, stream>>>(wh_arr, wi_arr, bs_arr, emb_arr, h_arr,
                                        fc_w, pt_arr, slots);
    finalize <<<1, 256, 0, stream>>>(pt_arr, fc_b, out);
}